// Round 17
// baseline (126.982 us; speedup 1.0000x reference)
//
#include <hip/hip_runtime.h>
#include <stdint.h>

#define M_DIM 8192
#define K_DIM 4096
#define N_DIM 4096

using i32x4 = __attribute__((ext_vector_type(4))) int;
using i32x8 = __attribute__((ext_vector_type(8))) int;
using f32x16 = __attribute__((ext_vector_type(16))) float;

typedef const __attribute__((address_space(1))) void g_void;
typedef __attribute__((address_space(3))) void lds_void;

__device__ __forceinline__ void gload_lds16(const void* g, void* l) {
  __builtin_amdgcn_global_load_lds((g_void*)g, (lds_void*)l, 16, 0, 0);
}

__device__ __forceinline__ void barrier_raw() {
  asm volatile("" ::: "memory");
  __builtin_amdgcn_s_barrier();
  asm volatile("" ::: "memory");
}

// fp4 e2m1: +1 = 0x2 (1.0), -1 = 0xA, 0 = 0x0
__device__ __forceinline__ unsigned code4(float v) {
  return v > 0.f ? 0x2u : (v < 0.f ? 0xAu : 0x0u);
}

// ---- pack x: fp32 [M][K] -> GEMM-ready fp4 [g=M/32][t=K/128][kc=4][row=32]x16B
__global__ void pack_x4_kernel(const float* __restrict__ in,
                               uint8_t* __restrict__ out) {
  __shared__ __align__(16) uint16_t cds[32 * 264];
  int g = blockIdx.x;
  int tq = blockIdx.y;
  int tid = threadIdx.x;
#pragma unroll
  for (int i = 0; i < 32; ++i) {
    int flat = tid + 256 * i;
    int row = flat >> 8;
    int c4 = flat & 255;
    const float4 v = *reinterpret_cast<const float4*>(
        in + (long)(g * 32 + row) * K_DIM + tq * 1024 + c4 * 4);
    unsigned u = code4(v.x) | (code4(v.y) << 4) | (code4(v.z) << 8) |
                 (code4(v.w) << 12);
    cds[row * 264 + c4] = (uint16_t)u;
  }
  __syncthreads();
#pragma unroll
  for (int j = 0; j < 4; ++j) {
    int u = tid + 256 * j;
    int tl = u >> 7;
    int kc = (u >> 5) & 3;
    int row = u & 31;
    i32x4 val = *reinterpret_cast<const i32x4*>(&cds[row * 264 + tl * 32 + kc * 8]);
    int t = tq * 8 + tl;
    long o = ((((long)g * 32 + t) * 4 + kc) * 32 + row) * 16;
    *reinterpret_cast<i32x4*>(out + o) = val;
  }
}

// ---- pack w: fp32 [K][N] -> GEMM-ready fp4 W^T [g=N/32][t][kc][row32]x16B
__global__ void pack_wt4_kernel(const float* __restrict__ w,
                                uint8_t* __restrict__ out) {
  __shared__ __align__(16) uint8_t tile[64 * 144];
  int n0 = blockIdx.x * 64;
  int k0 = blockIdx.y * 128;
  int tid = threadIdx.x;
#pragma unroll
  for (int i = 0; i < 32; ++i) {
    int flat = tid + 256 * i;
    int r = flat >> 6;
    int c = flat & 63;
    tile[c * 144 + r] = (uint8_t)code4(w[(long)(k0 + r) * N_DIM + n0 + c]);
  }
  __syncthreads();
  int rg = tid >> 7, kc = (tid >> 5) & 3, row = tid & 31;
  const unsigned* sp =
      reinterpret_cast<const unsigned*>(&tile[(rg * 32 + row) * 144 + kc * 32]);
  i32x4 val;
#pragma unroll
  for (int d = 0; d < 4; ++d) {
    unsigned s0 = sp[2 * d], s1 = sp[2 * d + 1];
    unsigned t0 = s0 & 0x0F0F0F0Fu, t1 = s1 & 0x0F0F0F0Fu;
    unsigned p = (t0 | (t0 >> 4)) & 0x00FF00FFu;
    unsigned q = (t1 | (t1 >> 4)) & 0x00FF00FFu;
    val[d] = (int)((p & 0xFFu) | ((p >> 8) & 0xFF00u) | ((q & 0xFFu) << 16) |
                   ((q >> 16) << 24));
  }
  int g = (n0 >> 5) + rg;
  int t = k0 >> 7;
  long o = ((((long)g * 32 + t) * 4 + kc) * 32 + row) * 16;
  *reinterpret_cast<i32x4*>(out + o) = val;
}

// ---- MX-fp4 GEMM: 128x256 tile, 4 waves, 2 async blocks/CU (R16 win)
//      + cross-barrier frag ping-pong (R15 schedule, now in-regime).
// Per tile t on the 3-slot ring:
//  a) lgkm(6)  -> MFMA h0(t)        [t.h1 reads drain underneath]
//  b) vmcnt(0) + barrier            [t+1 staged (issued at t-1.c), visible]
//  c) stage t+2 into slot (t+2)%3 + read 12 frags of t+1 (h0-first)
//  d) lgkm(12) -> MFMA h1(t)        [retires exactly t.h1; t+1 in flight]
// WAR: slot (t+2)%3=(t-1)%3; wave's last reads of it retired at its own
// t-1 step-d lgkm(12), before t's step-b barrier. Regs: 128 acc + 96
// ping-pong frags + ~20 addr = ~244 <= 256 (2 waves/SIMD).
__device__ __forceinline__ i32x8 lo8(i32x4 r) {
  return __builtin_shufflevector(r, r, 0, 1, 2, 3, -1, -1, -1, -1);
}

#define SCALE1 0x7f7f7f7f  // E8M0 1.0 in every byte

template <int VM, bool ISSUE, bool READ, int CUR>
__device__ __forceinline__ void tile_step(
    int t, const uint8_t* __restrict__ gA, const uint8_t* __restrict__ gB0,
    const uint8_t* __restrict__ gB1, int dstA, int dstB, uint8_t* lds,
    int aRd, int bRd, i32x4 (&aC)[8], i32x4 (&bC)[4], i32x4 (&aN)[8],
    i32x4 (&bN)[4], f32x16 (&acc)[4][2]) {
  // ---- a: MFMA h0(t) ----
  asm volatile("s_waitcnt lgkmcnt(6)" ::: "memory");  // t.h0 frags ready
  __builtin_amdgcn_sched_barrier(0);
  __builtin_amdgcn_s_setprio(1);
#pragma unroll
  for (int mi = 0; mi < 4; ++mi)
#pragma unroll
    for (int ni = 0; ni < 2; ++ni)
      acc[mi][ni] = __builtin_amdgcn_mfma_scale_f32_32x32x64_f8f6f4(
          lo8(aC[mi]), lo8(bC[ni]), acc[mi][ni], 4, 4, 0, SCALE1, 0, SCALE1);
  __builtin_amdgcn_s_setprio(0);
  // ---- b: vm-gate + single barrier per tile ----
  if (VM >= 0) {
    asm volatile("s_waitcnt vmcnt(0)" ::: "memory");
    barrier_raw();
  }
  // ---- c: stage t+2 + read t+1 frags (h0-first issue order) ----
  if (ISSUE) {
    long kn = (long)(t + 2) * 2048;
    uint8_t* nbuf = lds + ((CUR + 2) % 3) * 24576;
    gload_lds16(gA + kn, nbuf + dstA);
    gload_lds16(gA + kn + 1024, nbuf + dstA + 1024);
    gload_lds16(gB0 + kn, nbuf + dstB);
    gload_lds16(gB0 + kn + 1024, nbuf + dstB + 1024);
    gload_lds16(gB1 + kn, nbuf + dstB + 2048);
    gload_lds16(gB1 + kn + 1024, nbuf + dstB + 3072);
  }
  if (READ) {
    const uint8_t* nb = lds + ((CUR + 1) % 3) * 24576;
#pragma unroll
    for (int mi = 0; mi < 4; ++mi)
      aN[mi] = *reinterpret_cast<const i32x4*>(nb + aRd + mi * 2048);
#pragma unroll
    for (int ni = 0; ni < 2; ++ni)
      bN[ni] = *reinterpret_cast<const i32x4*>(nb + bRd + ni * 2048);
#pragma unroll
    for (int mi = 0; mi < 4; ++mi)
      aN[4 + mi] = *reinterpret_cast<const i32x4*>(nb + aRd + mi * 2048 + 1024);
#pragma unroll
    for (int ni = 0; ni < 2; ++ni)
      bN[2 + ni] = *reinterpret_cast<const i32x4*>(nb + bRd + ni * 2048 + 1024);
  }
  // ---- d: MFMA h1(t) ----
  if (READ)
    asm volatile("s_waitcnt lgkmcnt(12)" ::: "memory");  // retires t.h1 only
  else
    asm volatile("s_waitcnt lgkmcnt(0)" ::: "memory");
  __builtin_amdgcn_sched_barrier(0);
  __builtin_amdgcn_s_setprio(1);
#pragma unroll
  for (int mi = 0; mi < 4; ++mi)
#pragma unroll
    for (int ni = 0; ni < 2; ++ni)
      acc[mi][ni] = __builtin_amdgcn_mfma_scale_f32_32x32x64_f8f6f4(
          lo8(aC[4 + mi]), lo8(bC[2 + ni]), acc[mi][ni], 4, 4, 0, SCALE1, 0,
          SCALE1);
  __builtin_amdgcn_s_setprio(0);
}

__global__ __launch_bounds__(256, 2) void gemm_fp4_kernel(
    const uint8_t* __restrict__ A, const uint8_t* __restrict__ B,
    float* __restrict__ C) {
  __shared__ __align__(16) uint8_t lds[3 * 24576];  // 72 KiB

  // L2-locality XCD map: bijective over 64bm x 16bn, rectangle per XCD
  int bid = blockIdx.x;
  int xcd = bid & 7;
  int i = bid >> 3;                        // 0..127
  int bn = (i & 7) + ((xcd & 1) << 3);     // 0..15
  int bm = (i >> 3) + ((xcd >> 1) << 4);   // 0..63

  int tid = threadIdx.x;
  int wid = tid >> 6;  // 0..3 = N quarter; wave owns all 128 M-rows
  int lane = tid & 63;

  // staging bases (GEMM-ready layout, fully contiguous per issue)
  const uint8_t* gA = A + (long)(bm * 4 + wid) * 65536 + lane * 16;
  const uint8_t* gB0 = B + (long)(bn * 8 + 2 * wid) * 65536 + lane * 16;
  const uint8_t* gB1 = gB0 + 65536;
  int dstA = wid * 2048;           // A region [0, 8K)
  int dstB = 8192 + wid * 4096;    // B region [8K, 24K)

  // frag reads: A mb = mi (all waves share A), B nb = wid*2 + ni
  int aRd = lane * 16;
  int bRd = 8192 + (wid * 2) * 2048 + lane * 16;

  i32x4 aA[8], bA[4], aB[8], bB[4];
  f32x16 acc[4][2] = {};

  // prologue: stage tiles 0,1 (slots 0,1)
#pragma unroll
  for (int t = 0; t < 2; ++t) {
    uint8_t* buf = lds + t * 24576;
    long k0 = (long)t * 2048;
    gload_lds16(gA + k0, buf + dstA);
    gload_lds16(gA + k0 + 1024, buf + dstA + 1024);
    gload_lds16(gB0 + k0, buf + dstB);
    gload_lds16(gB0 + k0 + 1024, buf + dstB + 1024);
    gload_lds16(gB1 + k0, buf + dstB + 2048);
    gload_lds16(gB1 + k0 + 1024, buf + dstB + 3072);
  }
  asm volatile("s_waitcnt vmcnt(6)" ::: "memory");  // tile 0 landed
  barrier_raw();
  // read tile-0 frags into set A (h0-first: 6 then 6)
#pragma unroll
  for (int mi = 0; mi < 4; ++mi)
    aA[mi] = *reinterpret_cast<const i32x4*>(lds + aRd + mi * 2048);
#pragma unroll
  for (int ni = 0; ni < 2; ++ni)
    bA[ni] = *reinterpret_cast<const i32x4*>(lds + bRd + ni * 2048);
#pragma unroll
  for (int mi = 0; mi < 4; ++mi)
    aA[4 + mi] = *reinterpret_cast<const i32x4*>(lds + aRd + mi * 2048 + 1024);
#pragma unroll
  for (int ni = 0; ni < 2; ++ni)
    bA[2 + ni] = *reinterpret_cast<const i32x4*>(lds + bRd + ni * 2048 + 1024);

  // main loop: period 6 (3 slots x 2 frag-set parities), tiles 0..29
#pragma unroll 1
  for (int tt = 0; tt < 30; tt += 6) {
    tile_step<0, true, true, 0>(tt, gA, gB0, gB1, dstA, dstB, lds, aRd, bRd,
                                aA, bA, aB, bB, acc);
    tile_step<0, true, true, 1>(tt + 1, gA, gB0, gB1, dstA, dstB, lds, aRd,
                                bRd, aB, bB, aA, bA, acc);
    tile_step<0, true, true, 2>(tt + 2, gA, gB0, gB1, dstA, dstB, lds, aRd,
                                bRd, aA, bA, aB, bB, acc);
    tile_step<0, true, true, 0>(tt + 3, gA, gB0, gB1, dstA, dstB, lds, aRd,
                                bRd, aB, bB, aA, bA, acc);
    tile_step<0, true, true, 1>(tt + 4, gA, gB0, gB1, dstA, dstB, lds, aRd,
                                bRd, aA, bA, aB, bB, acc);
    tile_step<0, true, true, 2>(tt + 5, gA, gB0, gB1, dstA, dstB, lds, aRd,
                                bRd, aB, bB, aA, bA, acc);
  }
  // tails: t=30 (slot 0, uses A, reads 31 into B), t=31 (slot 1, uses B)
  tile_step<0, false, true, 0>(30, gA, gB0, gB1, dstA, dstB, lds, aRd, bRd,
                               aA, bA, aB, bB, acc);
  tile_step<-1, false, false, 1>(31, gA, gB0, gB1, dstA, dstB, lds, aRd, bRd,
                                 aB, bB, aA, bA, acc);

  // C/D 32x32 layout: col = lane&31, row = (reg&3) + 8*(reg>>2) + 4*(lane>>5)
  long row0 = (long)bm * 128 + ((lane >> 5) << 2);
  long col0 = (long)bn * 256 + wid * 64 + (lane & 31);
#pragma unroll
  for (int mi = 0; mi < 4; ++mi)
#pragma unroll
    for (int ni = 0; ni < 2; ++ni)
#pragma unroll
      for (int r = 0; r < 16; ++r) {
        long row = row0 + mi * 32 + (r & 3) + ((r >> 2) << 3);
        C[row * N_DIM + col0 + ni * 32] = acc[mi][ni][r];
      }
}

extern "C" void kernel_launch(void* const* d_in, const int* in_sizes, int n_in,
                              void* d_out, int out_size, void* d_ws, size_t ws_size,
                              hipStream_t stream) {
  const float* x = (const float*)d_in[0];
  const float* w = (const float*)d_in[1];
  float* out = (float*)d_out;

  uint8_t* x4 = (uint8_t*)d_ws;                     // 16 MB GEMM-ready A
  uint8_t* w4t = x4 + (size_t)M_DIM * (K_DIM / 2);  // 8 MB GEMM-ready W^T

  pack_x4_kernel<<<dim3(M_DIM / 32, 4), 256, 0, stream>>>(x, x4);
  pack_wt4_kernel<<<dim3(N_DIM / 64, K_DIM / 128), 256, 0, stream>>>(w, w4t);
  gemm_fp4_kernel<<<1024, 256, 0, stream>>>(x4, w4t, out);
}

// Round 18
// 125.374 us; speedup vs baseline: 1.0128x; 1.0128x over previous
//
#include <hip/hip_runtime.h>
#include <stdint.h>

#define M_DIM 8192
#define K_DIM 4096
#define N_DIM 4096

using i32x4 = __attribute__((ext_vector_type(4))) int;
using i32x8 = __attribute__((ext_vector_type(8))) int;
using f32x16 = __attribute__((ext_vector_type(16))) float;

typedef const __attribute__((address_space(1))) void g_void;
typedef __attribute__((address_space(3))) void lds_void;

__device__ __forceinline__ void gload_lds16(const void* g, void* l) {
  __builtin_amdgcn_global_load_lds((g_void*)g, (lds_void*)l, 16, 0, 0);
}

__device__ __forceinline__ void barrier_raw() {
  asm volatile("" ::: "memory");
  __builtin_amdgcn_s_barrier();
  asm volatile("" ::: "memory");
}

// fp4 e2m1: +1 = 0x2 (1.0), -1 = 0xA, 0 = 0x0
__device__ __forceinline__ unsigned code4(float v) {
  return v > 0.f ? 0x2u : (v < 0.f ? 0xAu : 0x0u);
}

// ---- pack x: fp32 [M][K] -> GEMM-ready fp4 [g=M/32][t=K/128][kc=4][row=32]x16B
__global__ void pack_x4_kernel(const float* __restrict__ in,
                               uint8_t* __restrict__ out) {
  __shared__ __align__(16) uint16_t cds[32 * 264];
  int g = blockIdx.x;
  int tq = blockIdx.y;
  int tid = threadIdx.x;
#pragma unroll
  for (int i = 0; i < 32; ++i) {
    int flat = tid + 256 * i;
    int row = flat >> 8;
    int c4 = flat & 255;
    const float4 v = *reinterpret_cast<const float4*>(
        in + (long)(g * 32 + row) * K_DIM + tq * 1024 + c4 * 4);
    unsigned u = code4(v.x) | (code4(v.y) << 4) | (code4(v.z) << 8) |
                 (code4(v.w) << 12);
    cds[row * 264 + c4] = (uint16_t)u;
  }
  __syncthreads();
#pragma unroll
  for (int j = 0; j < 4; ++j) {
    int u = tid + 256 * j;
    int tl = u >> 7;
    int kc = (u >> 5) & 3;
    int row = u & 31;
    i32x4 val = *reinterpret_cast<const i32x4*>(&cds[row * 264 + tl * 32 + kc * 8]);
    int t = tq * 8 + tl;
    long o = ((((long)g * 32 + t) * 4 + kc) * 32 + row) * 16;
    *reinterpret_cast<i32x4*>(out + o) = val;
  }
}

// ---- pack w: fp32 [K][N] -> GEMM-ready fp4 W^T [g=N/32][t][kc][row32]x16B
__global__ void pack_wt4_kernel(const float* __restrict__ w,
                                uint8_t* __restrict__ out) {
  __shared__ __align__(16) uint8_t tile[64 * 144];
  int n0 = blockIdx.x * 64;
  int k0 = blockIdx.y * 128;
  int tid = threadIdx.x;
#pragma unroll
  for (int i = 0; i < 32; ++i) {
    int flat = tid + 256 * i;
    int r = flat >> 6;
    int c = flat & 63;
    tile[c * 144 + r] = (uint8_t)code4(w[(long)(k0 + r) * N_DIM + n0 + c]);
  }
  __syncthreads();
  int rg = tid >> 7, kc = (tid >> 5) & 3, row = tid & 31;
  const unsigned* sp =
      reinterpret_cast<const unsigned*>(&tile[(rg * 32 + row) * 144 + kc * 32]);
  i32x4 val;
#pragma unroll
  for (int d = 0; d < 4; ++d) {
    unsigned s0 = sp[2 * d], s1 = sp[2 * d + 1];
    unsigned t0 = s0 & 0x0F0F0F0Fu, t1 = s1 & 0x0F0F0F0Fu;
    unsigned p = (t0 | (t0 >> 4)) & 0x00FF00FFu;
    unsigned q = (t1 | (t1 >> 4)) & 0x00FF00FFu;
    val[d] = (int)((p & 0xFFu) | ((p >> 8) & 0xFF00u) | ((q & 0xFFu) << 16) |
                   ((q >> 16) << 24));
  }
  int g = (n0 >> 5) + rg;
  int t = k0 >> 7;
  long o = ((((long)g * 32 + t) * 4 + kc) * 32 + row) * 16;
  *reinterpret_cast<i32x4*>(out + o) = val;
}

// ---- MX-fp4 GEMM: 128x256 tile, 4 waves, 2 async blocks/CU (R16 winner)
//      + B DIRECT global->VGPR (drops LDS port 1536 -> ~320 cyc/tile-pair).
// A (reused by all 4 waves) stays LDS-staged: ring 3 x 8 KB = 24 KB.
// B frag global read = 64 lanes x 16B = one 1KB coalesced segment
// (GEMM-ready layout; R6/R7's failure was the pre-R14 scatter layout).
// vmcnt ledger: per tile issue {B(t+2)x4, A(t+2)x2}; end-gate vmcnt(6)
// retires exactly {B(t+1), A(t+1)} (issued 1 tile ago > HBM latency).
// WAR: A slot (t+2)%3=(t-1)%3, reads retired at t-1's lgkm(0) before its
// end barrier (R16-proven). Regs: 128 acc + 48 B-sets + 32 A + ~15 = ~225.
__device__ __forceinline__ i32x8 lo8(i32x4 r) {
  return __builtin_shufflevector(r, r, 0, 1, 2, 3, -1, -1, -1, -1);
}

#define SCALE1 0x7f7f7f7f  // E8M0 1.0 in every byte

template <int VM, bool ISSUE, int CUR>
__device__ __forceinline__ void tile_step(
    int t, const uint8_t* __restrict__ gA, const uint8_t* __restrict__ gB,
    int dstA, uint8_t* lds, int aRd, i32x4 (&bC)[4], i32x4 (&bN)[4],
    f32x16 (&acc)[4][2]) {
  const uint8_t* buf = lds + CUR * 8192;
  // issue B(t+2) frag loads (4 x 1KB coalesced) + A(t+2) staging
  if (ISSUE) {
    long kn = (long)(t + 2) * 2048;
    bN[0] = *reinterpret_cast<const i32x4*>(gB + kn);                  // n0 h0
    bN[1] = *reinterpret_cast<const i32x4*>(gB + 65536 + kn);          // n1 h0
    bN[2] = *reinterpret_cast<const i32x4*>(gB + kn + 1024);           // n0 h1
    bN[3] = *reinterpret_cast<const i32x4*>(gB + 65536 + kn + 1024);   // n1 h1
    uint8_t* nbuf = lds + ((CUR + 2) % 3) * 8192;
    gload_lds16(gA + kn, nbuf + dstA);
    gload_lds16(gA + kn + 1024, nbuf + dstA + 1024);
  }
  // A frag reads (h0 first; lgkm(4) retires exactly h0)
  i32x4 a0[4], a1[4];
#pragma unroll
  for (int mi = 0; mi < 4; ++mi)
    a0[mi] = *reinterpret_cast<const i32x4*>(buf + aRd + mi * 2048);
#pragma unroll
  for (int mi = 0; mi < 4; ++mi)
    a1[mi] = *reinterpret_cast<const i32x4*>(buf + aRd + mi * 2048 + 1024);
  asm volatile("s_waitcnt lgkmcnt(4)" ::: "memory");
  __builtin_amdgcn_sched_barrier(0);
  __builtin_amdgcn_s_setprio(1);
#pragma unroll
  for (int mi = 0; mi < 4; ++mi)
#pragma unroll
    for (int ni = 0; ni < 2; ++ni)
      acc[mi][ni] = __builtin_amdgcn_mfma_scale_f32_32x32x64_f8f6f4(
          lo8(a0[mi]), lo8(bC[ni]), acc[mi][ni], 4, 4, 0, SCALE1, 0, SCALE1);
  __builtin_amdgcn_s_setprio(0);
  asm volatile("s_waitcnt lgkmcnt(0)" ::: "memory");
  __builtin_amdgcn_sched_barrier(0);
  __builtin_amdgcn_s_setprio(1);
#pragma unroll
  for (int mi = 0; mi < 4; ++mi)
#pragma unroll
    for (int ni = 0; ni < 2; ++ni)
      acc[mi][ni] = __builtin_amdgcn_mfma_scale_f32_32x32x64_f8f6f4(
          lo8(a1[mi]), lo8(bC[2 + ni]), acc[mi][ni], 4, 4, 0, SCALE1, 0,
          SCALE1);
  __builtin_amdgcn_s_setprio(0);
  // end-gate: tile t+1 ready (B(t+1) regs + A(t+1) LDS); 6 newer in flight
  if (VM >= 0) {
    if (VM == 6) asm volatile("s_waitcnt vmcnt(6)" ::: "memory");
    else asm volatile("s_waitcnt vmcnt(0)" ::: "memory");
    barrier_raw();
  }
}

__global__ __launch_bounds__(256, 2) void gemm_fp4_kernel(
    const uint8_t* __restrict__ A, const uint8_t* __restrict__ B,
    float* __restrict__ C) {
  __shared__ __align__(16) uint8_t lds[3 * 8192];  // 24 KiB, A only

  // L2-locality XCD map: bijective over 64bm x 16bn, rectangle per XCD
  int bid = blockIdx.x;
  int xcd = bid & 7;
  int i = bid >> 3;                        // 0..127
  int bn = (i & 7) + ((xcd & 1) << 3);     // 0..15
  int bm = (i >> 3) + ((xcd >> 1) << 4);   // 0..63

  int tid = threadIdx.x;
  int wid = tid >> 6;  // 0..3 = N quarter; wave owns all 128 M-rows
  int lane = tid & 63;

  // A staging base (contiguous 1KB per issue); B direct-read base
  const uint8_t* gA = A + (long)(bm * 4 + wid) * 65536 + lane * 16;
  const uint8_t* gB = B + (long)(bn * 8 + 2 * wid) * 65536 + lane * 16;
  int dstA = wid * 2048;  // 4 waves x 2KB = 8KB slot

  // A frag reads: mb = mi, half h -> mi*2048 + h*1024 + lane*16
  int aRd = lane * 16;

  i32x4 bs0[4], bs1[4], bs2[4];
  f32x16 acc[4][2] = {};

  // prologue: B(0)->bs0, A(0); B(1)->bs1, A(1)
  bs0[0] = *reinterpret_cast<const i32x4*>(gB);
  bs0[1] = *reinterpret_cast<const i32x4*>(gB + 65536);
  bs0[2] = *reinterpret_cast<const i32x4*>(gB + 1024);
  bs0[3] = *reinterpret_cast<const i32x4*>(gB + 65536 + 1024);
  gload_lds16(gA, lds + dstA);
  gload_lds16(gA + 1024, lds + dstA + 1024);
  bs1[0] = *reinterpret_cast<const i32x4*>(gB + 2048);
  bs1[1] = *reinterpret_cast<const i32x4*>(gB + 65536 + 2048);
  bs1[2] = *reinterpret_cast<const i32x4*>(gB + 3072);
  bs1[3] = *reinterpret_cast<const i32x4*>(gB + 65536 + 3072);
  gload_lds16(gA + 2048, lds + 8192 + dstA);
  gload_lds16(gA + 3072, lds + 8192 + dstA + 1024);
  asm volatile("s_waitcnt vmcnt(6)" ::: "memory");  // B(0)+A(0) landed
  barrier_raw();

  // main: period 3 (slot = B-set = t%3), tiles 0..29
#pragma unroll 1
  for (int tt = 0; tt < 30; tt += 3) {
    tile_step<6, true, 0>(tt, gA, gB, dstA, lds, aRd, bs0, bs2, acc);
    tile_step<6, true, 1>(tt + 1, gA, gB, dstA, lds, aRd, bs1, bs0, acc);
    tile_step<6, true, 2>(tt + 2, gA, gB, dstA, lds, aRd, bs2, bs1, acc);
  }
  tile_step<0, false, 0>(30, gA, gB, dstA, lds, aRd, bs0, bs2, acc);
  tile_step<-1, false, 1>(31, gA, gB, dstA, lds, aRd, bs1, bs0, acc);

  // C/D 32x32 layout: col = lane&31, row = (reg&3) + 8*(reg>>2) + 4*(lane>>5)
  long row0 = (long)bm * 128 + ((lane >> 5) << 2);
  long col0 = (long)bn * 256 + wid * 64 + (lane & 31);
#pragma unroll
  for (int mi = 0; mi < 4; ++mi)
#pragma unroll
    for (int ni = 0; ni < 2; ++ni)
#pragma unroll
      for (int r = 0; r < 16; ++r) {
        long row = row0 + mi * 32 + (r & 3) + ((r >> 2) << 3);
        C[row * N_DIM + col0 + ni * 32] = acc[mi][ni][r];
      }
}

extern "C" void kernel_launch(void* const* d_in, const int* in_sizes, int n_in,
                              void* d_out, int out_size, void* d_ws, size_t ws_size,
                              hipStream_t stream) {
  const float* x = (const float*)d_in[0];
  const float* w = (const float*)d_in[1];
  float* out = (float*)d_out;

  uint8_t* x4 = (uint8_t*)d_ws;                     // 16 MB GEMM-ready A
  uint8_t* w4t = x4 + (size_t)M_DIM * (K_DIM / 2);  // 8 MB GEMM-ready W^T

  pack_x4_kernel<<<dim3(M_DIM / 32, 4), 256, 0, stream>>>(x, x4);
  pack_wt4_kernel<<<dim3(N_DIM / 64, K_DIM / 128), 256, 0, stream>>>(w, w4t);
  gemm_fp4_kernel<<<1024, 256, 0, stream>>>(x4, w4t, out);
}